// Round 3
// baseline (950.827 us; speedup 1.0000x reference)
//
#include <hip/hip_runtime.h>
#include <hip/hip_bf16.h>
#include <math.h>

// Problem constants
#define B_   128
#define H_   512
#define TZ   64
#define TU   128
#define V_   8000
#define VC   8064            // V + TZ
#define LG   16064           // V + VC  (logits row length)
#define GIN  1541            // E + 2H + 5
#define G3   1536            // 3*H

__device__ __forceinline__ float sigmoidf_(float x){ return 1.f/(1.f+__expf(-x)); }

// ---------------------------------------------------------------------------
// Generic tiled GEMM:  C[M,N] = A[M,K] @ W[N,K]^T + bias[N]
// M, N multiples of 64; K arbitrary. 256 threads, 64x64 tile, 4x4 micro-tile.
// ---------------------------------------------------------------------------
__global__ __launch_bounds__(256) void gemm_bias(
    const float* __restrict__ A, int lda,
    const float* __restrict__ W, int ldw,
    const float* __restrict__ bias,
    float* __restrict__ C, int ldc,
    int M, int N, int K)
{
  __shared__ float As[16][64];
  __shared__ float Ws[16][64];
  const int tid = threadIdx.x;
  const int tx = tid & 15, ty = tid >> 4;
  const int bm = blockIdx.y * 64, bn = blockIdx.x * 64;
  const int lrow = tid >> 2, lk = (tid & 3) << 2;
  float acc[4][4] = {};
  for (int k0 = 0; k0 < K; k0 += 16) {
#pragma unroll
    for (int i = 0; i < 4; ++i) {
      int k = k0 + lk + i;
      As[lk+i][lrow] = (k < K) ? A[(size_t)(bm+lrow)*lda + k] : 0.f;
      Ws[lk+i][lrow] = (k < K) ? W[(size_t)(bn+lrow)*ldw + k] : 0.f;
    }
    __syncthreads();
#pragma unroll
    for (int kk = 0; kk < 16; ++kk) {
      float4 av = *(const float4*)&As[kk][ty<<2];
      float4 bv = *(const float4*)&Ws[kk][tx<<2];
      float a[4] = {av.x, av.y, av.z, av.w};
      float b[4] = {bv.x, bv.y, bv.z, bv.w};
#pragma unroll
      for (int i = 0; i < 4; ++i)
#pragma unroll
        for (int j = 0; j < 4; ++j)
          acc[i][j] += a[i] * b[j];
    }
    __syncthreads();
  }
#pragma unroll
  for (int i = 0; i < 4; ++i) {
    int m = bm + (ty<<2) + i;
#pragma unroll
    for (int j = 0; j < 4; ++j) {
      int n = bn + (tx<<2) + j;
      C[(size_t)m*ldc + n] = acc[i][j] + bias[n];
    }
  }
}

// ---------------------------------------------------------------------------
// Fused attention-energy GEMM + reduce:
//   A rows are enc flattened (T*B, 512); row m -> t = m/B, b = m%B.
//   score[b*T+t] += sum_n tanh(acc[m][n] + add[b*add_stride + n]) * mul[b*mul_stride + n]
// M = T*B (mult of 64), N = K = 512 fixed. Grid (512/64, M/64).
// scores must be zeroed before launch (global atomicAdd across the 8 N-blocks).
// ---------------------------------------------------------------------------
__global__ __launch_bounds__(256) void attn_energy(
    const float* __restrict__ A,
    const float* __restrict__ W, int ldw,
    const float* __restrict__ add, int add_stride,
    const float* __restrict__ mul, int mul_stride,
    float* __restrict__ scores, int T)
{
  __shared__ float As[16][64];
  __shared__ float Ws[16][64];
  __shared__ float sred[64];
  const int tid = threadIdx.x;
  const int tx = tid & 15, ty = tid >> 4;
  const int bm = blockIdx.y * 64, bn = blockIdx.x * 64;
  const int lrow = tid >> 2, lk = (tid & 3) << 2;
  float acc[4][4] = {};
  for (int k0 = 0; k0 < 512; k0 += 16) {
    {
      const float* p = A + (size_t)(bm+lrow)*512 + k0 + lk;
      float4 x = *(const float4*)p;
      As[lk+0][lrow]=x.x; As[lk+1][lrow]=x.y; As[lk+2][lrow]=x.z; As[lk+3][lrow]=x.w;
      const float* q = W + (size_t)(bn+lrow)*ldw + k0 + lk;
      float4 y = *(const float4*)q;
      Ws[lk+0][lrow]=y.x; Ws[lk+1][lrow]=y.y; Ws[lk+2][lrow]=y.z; Ws[lk+3][lrow]=y.w;
    }
    __syncthreads();
#pragma unroll
    for (int kk = 0; kk < 16; ++kk) {
      float4 av = *(const float4*)&As[kk][ty<<2];
      float4 bv = *(const float4*)&Ws[kk][tx<<2];
      float a[4] = {av.x, av.y, av.z, av.w};
      float b[4] = {bv.x, bv.y, bv.z, bv.w};
#pragma unroll
      for (int i = 0; i < 4; ++i)
#pragma unroll
        for (int j = 0; j < 4; ++j)
          acc[i][j] += a[i] * b[j];
    }
    __syncthreads();
  }
  // Epilogue: tanh, scale by mul, reduce over the 64 columns of this tile.
#pragma unroll
  for (int i = 0; i < 4; ++i) {
    int m = bm + (ty<<2) + i;
    int b = m & (B_-1);
    float part = 0.f;
#pragma unroll
    for (int j = 0; j < 4; ++j) {
      int n = bn + (tx<<2) + j;
      float val = tanhf(acc[i][j] + add[(size_t)b*add_stride + n]);
      part += val * mul[(size_t)b*mul_stride + n];
    }
    // reduce across the 16 tx lanes holding this row (consecutive lanes)
#pragma unroll
    for (int off = 8; off; off >>= 1) part += __shfl_down(part, off, 16);
    if (tx == 0) sred[(ty<<2)+i] = part;
  }
  __syncthreads();
  if (tid < 64) {
    int m = bm + tid;
    int b = m & (B_-1), t = m >> 7;       // B_ = 128
    atomicAdd(&scores[b*T + t], sred[tid]);
  }
}

// ---------------------------------------------------------------------------
// Per-batch attention softmax over T scores + context: ctx[b,h] = sum_t a[t]*enc[t,b,h]
// ---------------------------------------------------------------------------
__global__ __launch_bounds__(256) void attn_soft_ctx(
    const float* __restrict__ scores, const float* __restrict__ enc,
    float* __restrict__ ctx, int T)
{
  const int b = blockIdx.x, tid = threadIdx.x;
  __shared__ float sa[256];
  __shared__ float aw[128];
  float s = (tid < T) ? scores[b*T + tid] : -INFINITY;
  sa[tid] = s; __syncthreads();
  for (int o = 128; o > 0; o >>= 1) { if (tid < o) sa[tid] = fmaxf(sa[tid], sa[tid+o]); __syncthreads(); }
  float mx = sa[0]; __syncthreads();
  float e = (tid < T) ? __expf(s - mx) : 0.f;
  sa[tid] = e; __syncthreads();
  for (int o = 128; o > 0; o >>= 1) { if (tid < o) sa[tid] += sa[tid+o]; __syncthreads(); }
  float inv = 1.f / sa[0];
  if (tid < T) aw[tid] = e * inv;
  __syncthreads();
  for (int h = tid; h < H_; h += 256) {
    float acc = 0.f;
    for (int t = 0; t < T; ++t)
      acc += aw[t] * enc[((size_t)t*B_ + b)*H_ + h];
    ctx[(size_t)b*H_ + h] = acc;
  }
}

// ---------------------------------------------------------------------------
// Build gru_in (B,1541) = [emb[m_t[b]], u_ctx, z_ctx, degree] and cat3[:, :1024] = [z_ctx, u_ctx]
// ---------------------------------------------------------------------------
__global__ __launch_bounds__(256) void concat_kernel(
    const int* __restrict__ m_t, const float* __restrict__ emb,
    const float* __restrict__ uctx, const float* __restrict__ zctx,
    const float* __restrict__ degree,
    float* __restrict__ gru_in, float* __restrict__ cat3)
{
  const int b = blockIdx.x, tid = threadIdx.x;
  const float* e = emb + (size_t)m_t[b] * H_;
  for (int i = tid; i < H_; i += 256) {
    float uz = uctx[(size_t)b*H_ + i];
    float zz = zctx[(size_t)b*H_ + i];
    gru_in[(size_t)b*GIN + i]          = e[i];
    gru_in[(size_t)b*GIN + H_ + i]     = uz;
    gru_in[(size_t)b*GIN + 2*H_ + i]   = zz;
    cat3[(size_t)b*G3 + i]             = zz;
    cat3[(size_t)b*G3 + H_ + i]        = uz;
  }
  if (tid < 5) gru_in[(size_t)b*GIN + 3*H_ + tid] = degree[b*5 + tid];
}

// ---------------------------------------------------------------------------
// GRU pointwise; writes h_new to ws, cat3[:,1024:1536], and both gru_out outputs.
// ---------------------------------------------------------------------------
__global__ __launch_bounds__(256) void gru_kernel(
    const float* __restrict__ gi, const float* __restrict__ gh,
    const float* __restrict__ hprev,
    float* __restrict__ hnew, float* __restrict__ cat3,
    float* __restrict__ out1, float* __restrict__ out2)
{
  int idx = blockIdx.x*256 + threadIdx.x;        // B*H
  int b = idx >> 9, h = idx & (H_-1);
  float ir = gi[(size_t)b*G3 + h],        hr = gh[(size_t)b*G3 + h];
  float iz = gi[(size_t)b*G3 + H_ + h],   hz = gh[(size_t)b*G3 + H_ + h];
  float in_= gi[(size_t)b*G3 + 2*H_ + h], hn = gh[(size_t)b*G3 + 2*H_ + h];
  float r = sigmoidf_(ir + hr);
  float z = sigmoidf_(iz + hz);
  float n = tanhf(in_ + r*hn);
  float hv = (1.f - z)*n + z*hprev[idx];
  hnew[idx] = hv;
  cat3[(size_t)b*G3 + 2*H_ + h] = hv;
  out1[idx] = hv;
  out2[idx] = hv;
}

// ---------------------------------------------------------------------------
// z_score -> per-row max + exp
// ---------------------------------------------------------------------------
__global__ __launch_bounds__(64) void zexp_kernel(
    const float* __restrict__ zscore, float* __restrict__ e, float* __restrict__ mbuf)
{
  const int b = blockIdx.x, tid = threadIdx.x;   // 64 threads
  __shared__ float sa[64];
  float s = zscore[b*TZ + tid];
  sa[tid] = s; __syncthreads();
  for (int o = 32; o > 0; o >>= 1) { if (tid < o) sa[tid] = fmaxf(sa[tid], sa[tid+o]); __syncthreads(); }
  float mx = sa[0];
  e[b*TZ + tid] = __expf(s - mx);
  if (tid == 0) mbuf[b] = mx;
}

// ---------------------------------------------------------------------------
// z_copy[b,v] = log(sum_t e[t] * sr[b,t,v]) + m[b]  -> logits[b, 8000+v]
// The 264 MB sparse_response read lives here (HBM-bound).
// ---------------------------------------------------------------------------
__global__ __launch_bounds__(256) void zcopy_kernel(
    const float* __restrict__ e, const float* __restrict__ mbuf,
    const float* __restrict__ sr, float* __restrict__ logits)
{
  const int b = blockIdx.y;
  const int v0 = blockIdx.x*1024 + threadIdx.x*4;
  __shared__ float se[TZ];
  if (threadIdx.x < TZ) se[threadIdx.x] = e[b*TZ + threadIdx.x];
  __syncthreads();
  if (v0 >= VC) return;
  float4 acc = {0.f, 0.f, 0.f, 0.f};
  const float* base = sr + (size_t)b*TZ*VC;
#pragma unroll 4
  for (int t = 0; t < TZ; ++t) {
    float et = se[t];
    float4 x = *(const float4*)(base + (size_t)t*VC + v0);
    acc.x += et*x.x; acc.y += et*x.y; acc.z += et*x.z; acc.w += et*x.w;
  }
  float m = mbuf[b];
  float* out = logits + (size_t)b*LG + V_ + v0;
  out[0] = __logf(acc.x) + m;
  out[1] = __logf(acc.y) + m;
  out[2] = __logf(acc.z) + m;
  out[3] = __logf(acc.w) + m;
}

// ---------------------------------------------------------------------------
// Final softmax over 16064 logits per row; proba = [gen + cp[:V], cp[V:]]
// ---------------------------------------------------------------------------
__global__ __launch_bounds__(256) void final_softmax(
    const float* __restrict__ logits, float* __restrict__ out0)
{
  const int b = blockIdx.x, tid = threadIdx.x;
  const float* row = logits + (size_t)b*LG;
  __shared__ float sa[256];
  float mx = -INFINITY;
  for (int i = tid; i < LG; i += 256) mx = fmaxf(mx, row[i]);
  sa[tid] = mx; __syncthreads();
  for (int o = 128; o > 0; o >>= 1) { if (tid < o) sa[tid] = fmaxf(sa[tid], sa[tid+o]); __syncthreads(); }
  mx = sa[0]; __syncthreads();
  float sum = 0.f;
  for (int i = tid; i < LG; i += 256) sum += __expf(row[i] - mx);
  sa[tid] = sum; __syncthreads();
  for (int o = 128; o > 0; o >>= 1) { if (tid < o) sa[tid] += sa[tid+o]; __syncthreads(); }
  float inv = 1.f / sa[0];
  float* o0 = out0 + (size_t)b*VC;
  for (int j = tid; j < V_; j += 256)
    o0[j] = (__expf(row[j]-mx) + __expf(row[V_+j]-mx)) * inv;
  for (int j = tid; j < TZ; j += 256)
    o0[V_ + j] = __expf(row[2*V_ + j] - mx) * inv;
}

// ---------------------------------------------------------------------------
extern "C" void kernel_launch(void* const* d_in, const int* in_sizes, int n_in,
                              void* d_out, int out_size, void* d_ws, size_t ws_size,
                              hipStream_t stream)
{
  const float* z_enc   = (const float*)d_in[0];   // (64,128,512)
  const float* u_enc   = (const float*)d_in[1];   // (128,128,512)
  const int*   m_t     = (const int*)  d_in[2];   // (1,128)
  const float* degree  = (const float*)d_in[3];   // (128,5)
  const float* hidden  = (const float*)d_in[4];   // (1,128,512)
  const float* sr      = (const float*)d_in[5];   // (128,64,8064)
  const float* emb     = (const float*)d_in[6];   // (8000,512)
  const float* attn_z_W= (const float*)d_in[7];   // (512,1024)
  const float* attn_z_b= (const float*)d_in[8];
  const float* attn_z_v= (const float*)d_in[9];
  const float* attn_u_W= (const float*)d_in[10];
  const float* attn_u_b= (const float*)d_in[11];
  const float* attn_u_v= (const float*)d_in[12];
  const float* gru_W_ih= (const float*)d_in[13];  // (1536,1541)
  const float* gru_W_hh= (const float*)d_in[14];  // (1536,512)
  const float* gru_b_ih= (const float*)d_in[15];
  const float* gru_b_hh= (const float*)d_in[16];
  const float* proj_W  = (const float*)d_in[17];  // (8000,1536)
  const float* proj_b  = (const float*)d_in[18];
  const float* copy2_W = (const float*)d_in[19];  // (512,512)
  const float* copy2_b = (const float*)d_in[20];

  float* out0 = (float*)d_out;                        // (128, 8064)
  float* out1 = out0 + (size_t)B_*VC;                 // (128, 512)
  float* out2 = out1 + (size_t)B_*H_;                 // (128, 512)

  // Workspace layout (floats)
  float* ws      = (float*)d_ws;
  float* hWz     = ws;                    // 128*512
  float* hWu     = hWz  + B_*H_;          // 128*512
  float* gh      = hWu  + B_*H_;          // 128*1536
  float* scoresZ = gh   + B_*G3;          // 128*64 (zeroed)
  float* scoresU = scoresZ + B_*TZ;       // 128*128 (zeroed)
  float* zscore  = scoresU + B_*TU;       // 128*64 (zeroed)
  float* zctx    = zscore  + B_*TZ;       // 128*512
  float* uctx    = zctx + B_*H_;          // 128*512
  float* gru_in  = uctx + B_*H_;          // 128*1541
  float* gi      = gru_in + B_*GIN;       // 128*1536
  float* hnew    = gi   + B_*G3;          // 128*512
  float* cat3    = hnew + B_*H_;          // 128*1536
  float* ez      = cat3 + B_*G3;          // 128*64
  float* mz      = ez   + B_*TZ;          // 128
  float* logits  = mz   + B_;             // 128*16064

  // zero the atomic-accumulated score buffers
  (void)hipMemsetAsync(scoresZ, 0, (size_t)(B_*TZ + B_*TU + B_*TZ)*sizeof(float), stream);

  // hidden-side precompute
  gemm_bias<<<dim3(H_/64, B_/64), 256, 0, stream>>>(hidden, H_, attn_z_W, 2*H_, attn_z_b, hWz, H_, B_, H_, H_);
  gemm_bias<<<dim3(H_/64, B_/64), 256, 0, stream>>>(hidden, H_, attn_u_W, 2*H_, attn_u_b, hWu, H_, B_, H_, H_);
  gemm_bias<<<dim3(G3/64, B_/64), 256, 0, stream>>>(hidden, H_, gru_W_hh, H_, gru_b_hh, gh, G3, B_, G3, H_);

  // attention energies + scores
  attn_energy<<<dim3(H_/64, TZ*B_/64), 256, 0, stream>>>(z_enc, attn_z_W + H_, 2*H_, hWz, H_, attn_z_v, 0, scoresZ, TZ);
  attn_energy<<<dim3(H_/64, TU*B_/64), 256, 0, stream>>>(u_enc, attn_u_W + H_, 2*H_, hWu, H_, attn_u_v, 0, scoresU, TU);

  // softmax + context
  attn_soft_ctx<<<B_, 256, 0, stream>>>(scoresZ, z_enc, zctx, TZ);
  attn_soft_ctx<<<B_, 256, 0, stream>>>(scoresU, u_enc, uctx, TU);

  // GRU input concat, input GEMM, pointwise GRU
  concat_kernel<<<B_, 256, 0, stream>>>(m_t, emb, uctx, zctx, degree, gru_in, cat3);
  gemm_bias<<<dim3(G3/64, B_/64), 256, 0, stream>>>(gru_in, GIN, gru_W_ih, GIN, gru_b_ih, gi, G3, B_, G3, GIN);
  gru_kernel<<<(B_*H_)/256, 256, 0, stream>>>(gi, gh, hidden, hnew, cat3, out1, out2);

  // generation logits -> logits[:, 0:8000]
  gemm_bias<<<dim3(V_/64, B_/64), 256, 0, stream>>>(cat3, G3, proj_W, G3, proj_b, logits, LG, B_, V_, G3);

  // copy scores
  attn_energy<<<dim3(H_/64, TZ*B_/64), 256, 0, stream>>>(z_enc, copy2_W, H_, copy2_b, 0, hnew, H_, zscore, TZ);
  zexp_kernel<<<B_, 64, 0, stream>>>(zscore, ez, mz);
  zcopy_kernel<<<dim3((VC + 1023)/1024, B_), 256, 0, stream>>>(ez, mz, sr, logits);

  // final fused softmax + output assembly
  final_softmax<<<B_, 256, 0, stream>>>(logits, out0);
}